// Round 6
// baseline (265.520 us; speedup 1.0000x reference)
//
#include <hip/hip_runtime.h>

#define NROWS 8000
#define DDIM 9
#define NCOL4 (NROWS / 4)      // 2000 float4 per output row
#define ROWS_PER_BLK 50        // 160 row-chunks in grid.y
#define NCHUNK 125             // 8000 rows / 64 rows-per-wave

typedef float f32x4 __attribute__((ext_vector_type(4)));

// ---------------------------------------------------------------------------
// K1: one wave per 64-row chunk. Per row: s = sum_j ((x-c)/a)^2, f = x.w+b.
// Wave-level inclusive scan (shuffles, no barriers) -> local cumsums cs1,cs2;
// lane 63 writes chunk totals.
// ---------------------------------------------------------------------------
__global__ __launch_bounds__(256)
void anfis_rows(const float* __restrict__ x,
                const float* __restrict__ a1p, const float* __restrict__ c1p,
                const float* __restrict__ a2p, const float* __restrict__ c2p,
                const float* __restrict__ w_fc1, const float* __restrict__ b_fc1,
                const float* __restrict__ w_fc2, const float* __restrict__ b_fc2,
                float* __restrict__ cs1o, float* __restrict__ cs2o,
                float2* __restrict__ f12o,
                float* __restrict__ t1o, float* __restrict__ t2o) {
    const int wid  = (blockIdx.x * 256 + threadIdx.x) >> 6;   // chunk id
    const int lane = threadIdx.x & 63;
    if (wid >= NCHUNK) return;
    const int r = wid * 64 + lane;

    const float inv_a1 = 1.0f / a1p[0];
    const float c1 = c1p[0];
    const float inv_a2 = 1.0f / a2p[0];
    const float c2 = c2p[0];

    float s1 = 0.f, s2 = 0.f, d1 = 0.f, d2 = 0.f;
#pragma unroll
    for (int j = 0; j < DDIM; ++j) {
        float xv = x[r * DDIM + j];
        float u1 = (xv - c1) * inv_a1;
        float u2 = (xv - c2) * inv_a2;
        s1 += u1 * u1;
        s2 += u2 * u2;
        d1 += xv * w_fc1[j];
        d2 += xv * w_fc2[j];
    }
    f12o[r] = make_float2(d1 + b_fc1[0], d2 + b_fc2[0]);

    // inclusive wave scan over 64 lanes
#pragma unroll
    for (int d = 1; d < 64; d <<= 1) {
        float n1 = __shfl_up(s1, d, 64);
        float n2 = __shfl_up(s2, d, 64);
        if (lane >= d) { s1 += n1; s2 += n2; }
    }
    cs1o[r] = s1;
    cs2o[r] = s2;
    if (lane == 63) { t1o[wid] = s1; t2o[wid] = s2; }
}

// ---------------------------------------------------------------------------
// K2 (8 blocks): chunk-total scan (redundant per block, cheap) + compute
// w1b/w2b arrays so the streaming kernel does zero math:
//   a = cs1[j]+P1[chunk], b = cs2[j]+P2[chunk]
//   w1b = 1/(1+exp(a-b)), w2b = 1-w1b   (log-space cumprod normalization)
// ---------------------------------------------------------------------------
__global__ __launch_bounds__(256)
void anfis_weights(const float* __restrict__ cs1, const float* __restrict__ cs2,
                   const float* __restrict__ t1, const float* __restrict__ t2,
                   f32x4* __restrict__ w1b4, f32x4* __restrict__ w2b4) {
    __shared__ float sh1[128];
    __shared__ float sh2[128];
    const int tid = threadIdx.x;

    if (tid < 128) {
        sh1[tid] = (tid < NCHUNK) ? t1[tid] : 0.f;
        sh2[tid] = (tid < NCHUNK) ? t2[tid] : 0.f;
    }
    __syncthreads();
    for (int off = 1; off < 128; off <<= 1) {
        float v1 = 0.f, v2 = 0.f;
        if (tid < 128 && tid >= off) { v1 = sh1[tid - off]; v2 = sh2[tid - off]; }
        __syncthreads();
        if (tid < 128) { sh1[tid] += v1; sh2[tid] += v2; }
        __syncthreads();
    }

    const int j4 = blockIdx.x * 256 + tid;   // float4 column index
    if (j4 >= NCOL4) return;
    const int c = j4 >> 4;                   // chunk of these 4 cols
    const float pre1 = (c > 0) ? sh1[c - 1] : 0.f;   // exclusive prefix
    const float pre2 = (c > 0) ? sh2[c - 1] : 0.f;
    f32x4 a = ((const f32x4*)cs1)[j4] + pre1;
    f32x4 b = ((const f32x4*)cs2)[j4] + pre2;
    f32x4 u, v;
#pragma unroll
    for (int q = 0; q < 4; ++q) {
        float e = expf(a[q] - b[q]);
        float inv = 1.0f / (1.0f + e);
        u[q] = inv;        // w1_bar
        v[q] = e * inv;    // w2_bar
    }
    w1b4[j4] = u;
    w2b4[j4] = v;
}

// ---------------------------------------------------------------------------
// K3: pure streamer. out[i][j] = f1[i]*w1b[j] + f2[i]*w2b[j].
// Two 16B loads (L2-resident) + 50 plain dwordx4 stores per thread.
// No LDS, no barriers. 1280 blocks.
// ---------------------------------------------------------------------------
__global__ __launch_bounds__(256)
void anfis_out(const float2* __restrict__ f12,
               const f32x4* __restrict__ w1b4, const f32x4* __restrict__ w2b4,
               float* __restrict__ out) {
    const int j4 = blockIdx.x * 256 + threadIdx.x;  // float4 column index
    if (j4 >= NCOL4) return;

    const f32x4 u = w1b4[j4];
    const f32x4 v = w2b4[j4];

    const int i0 = blockIdx.y * ROWS_PER_BLK;
    f32x4* orow = (f32x4*)out + (size_t)i0 * NCOL4 + j4;
#pragma unroll 4
    for (int k = 0; k < ROWS_PER_BLK; ++k) {
        const float2 ab = f12[i0 + k];   // block-uniform -> scalar load
        f32x4 o = ab.x * u + ab.y * v;
        *orow = o;
        orow += NCOL4;
    }
}

// ---------------------------------------------------------------------------
extern "C" void kernel_launch(void* const* d_in, const int* in_sizes, int n_in,
                              void* d_out, int out_size, void* d_ws, size_t ws_size,
                              hipStream_t stream) {
    const float* x     = (const float*)d_in[0];
    const float* a1    = (const float*)d_in[1];
    const float* c1    = (const float*)d_in[2];
    const float* a2    = (const float*)d_in[3];
    const float* c2    = (const float*)d_in[4];
    const float* w_fc1 = (const float*)d_in[5];
    const float* b_fc1 = (const float*)d_in[6];
    const float* w_fc2 = (const float*)d_in[7];
    const float* b_fc2 = (const float*)d_in[8];
    float* out = (float*)d_out;

    float* ws    = (float*)d_ws;          // ~195 KB used
    float* cs1   = ws;                    // [8000] local inclusive cumsums
    float* cs2   = ws + 8000;
    float2* f12  = (float2*)(ws + 16000); // [8000] float2
    float* t1    = ws + 32000;            // [125] chunk totals
    float* t2    = ws + 32128;            // (aligned gaps)
    f32x4* w1b4  = (f32x4*)(ws + 32256);  // [2000] f32x4
    f32x4* w2b4  = (f32x4*)(ws + 40256);  // [2000] f32x4

    anfis_rows<<<(NCHUNK * 64 + 255) / 256, 256, 0, stream>>>(
        x, a1, c1, a2, c2, w_fc1, b_fc1, w_fc2, b_fc2, cs1, cs2, f12, t1, t2);
    anfis_weights<<<(NCOL4 + 255) / 256, 256, 0, stream>>>(
        cs1, cs2, t1, t2, w1b4, w2b4);
    anfis_out<<<dim3((NCOL4 + 255) / 256, NROWS / ROWS_PER_BLK), 256, 0, stream>>>(
        f12, w1b4, w2b4, out);
}